// Round 3
// baseline (380.811 us; speedup 1.0000x reference)
//
#include <hip/hip_runtime.h>

#define HDIM 1024
#define BDIM 32
#define LDIM 1024

// ws layout (floats): u1[0:H], u2[H:2H], vbar[2H : 2H+B*H], logits[2H+B*H : +B*L]

// u1[h] = sum_o W[o,h]*w1[o]; u2[h] = sum_o W[o,h]*w2[o]. Coalesced row reads.
__global__ __launch_bounds__(256) void k_u12(const float4* __restrict__ W4,
                                             const float* __restrict__ mlp_w,
                                             float* __restrict__ u1,
                                             float* __restrict__ u2) {
    int t  = threadIdx.x;            // float4 index within a row, [0,256)
    int o0 = blockIdx.x * 16;        // 64 blocks x 16 rows
    float4 s1 = make_float4(0.f, 0.f, 0.f, 0.f);
    float4 s2 = make_float4(0.f, 0.f, 0.f, 0.f);
    #pragma unroll 4
    for (int o = o0; o < o0 + 16; ++o) {
        float4 w = W4[o * 256 + t];
        float c1 = mlp_w[o];
        float c2 = mlp_w[HDIM + o];
        s1.x += w.x * c1; s1.y += w.y * c1; s1.z += w.z * c1; s1.w += w.w * c1;
        s2.x += w.x * c2; s2.y += w.y * c2; s2.z += w.z * c2; s2.w += w.w * c2;
    }
    int h = t * 4;
    atomicAdd(&u1[h + 0], s1.x); atomicAdd(&u1[h + 1], s1.y);
    atomicAdd(&u1[h + 2], s1.z); atomicAdd(&u1[h + 3], s1.w);
    atomicAdd(&u2[h + 0], s2.x); atomicAdd(&u2[h + 1], s2.y);
    atomicAdd(&u2[h + 2], s2.z); atomicAdd(&u2[h + 3], s2.w);
}

// logits[row] = relu(q[row]·u1 + k[row]·u2 + b).
// Wave handles 8 rows in 2 groups of 4; all 32 float4 loads of a group issued
// before use (deep MLP); u1/u2 fragments pinned in 32 VGPRs for the kernel.
// __launch_bounds__(256,2): VGPR cap 256 so the pipeline actually fits.
__global__ __launch_bounds__(256, 2) void k_logits(const float4* __restrict__ q,
                                                   const float4* __restrict__ k,
                                                   const float4* __restrict__ u1v,
                                                   const float4* __restrict__ u2v,
                                                   const float* __restrict__ mlp_b,
                                                   float4* __restrict__ logits4) {
    int t = threadIdx.x;
    int lane = t & 63, wave = t >> 6;
    float4 b1[4], b2[4];
    #pragma unroll
    for (int i = 0; i < 4; ++i) {
        b1[i] = u1v[lane + 64 * i];
        b2[i] = u2v[lane + 64 * i];
    }
    float bias = mlp_b[0];
    long long base = (long long)blockIdx.x * 32 + wave * 8;  // 1024 blocks, 32 rows each
    #pragma unroll 1
    for (int g = 0; g < 2; ++g) {
        long long row0 = base + g * 4;
        float4 x[4][4], y[4][4];
        #pragma unroll
        for (int r = 0; r < 4; ++r) {
            const float4* qr = q + (row0 + r) * 256 + lane;
            const float4* kr = k + (row0 + r) * 256 + lane;
            #pragma unroll
            for (int i = 0; i < 4; ++i) {
                x[r][i] = qr[64 * i];
                y[r][i] = kr[64 * i];
            }
        }
        float acc[4];
        #pragma unroll
        for (int r = 0; r < 4; ++r) {
            float a = 0.f;
            #pragma unroll
            for (int i = 0; i < 4; ++i) {
                a += x[r][i].x * b1[i].x + x[r][i].y * b1[i].y
                   + x[r][i].z * b1[i].z + x[r][i].w * b1[i].w;
                a += y[r][i].x * b2[i].x + y[r][i].y * b2[i].y
                   + y[r][i].z * b2[i].z + y[r][i].w * b2[i].w;
            }
            acc[r] = a;
        }
        #pragma unroll
        for (int off = 32; off > 0; off >>= 1) {
            #pragma unroll
            for (int r = 0; r < 4; ++r)
                acc[r] += __shfl_down(acc[r], off, 64);
        }
        if (lane == 0) {
            float4 o;
            o.x = fmaxf(acc[0] + bias, 0.f);
            o.y = fmaxf(acc[1] + bias, 0.f);
            o.z = fmaxf(acc[2] + bias, 0.f);
            o.w = fmaxf(acc[3] + bias, 0.f);
            logits4[row0 >> 2] = o;
        }
    }
}

__global__ __launch_bounds__(256) void k_softmax(const float* __restrict__ logits,
                                                 float* __restrict__ score) {
    __shared__ float sm[4];
    __shared__ float ss[4];
    int b = blockIdx.x;
    int t = threadIdx.x;
    int wave = t >> 6, lane = t & 63;
    float4 v = ((const float4*)(logits + b * LDIM))[t];
    float m = fmaxf(fmaxf(v.x, v.y), fmaxf(v.z, v.w));
    #pragma unroll
    for (int off = 32; off > 0; off >>= 1)
        m = fmaxf(m, __shfl_down(m, off, 64));
    if (lane == 0) sm[wave] = m;
    __syncthreads();
    float M = fmaxf(fmaxf(sm[0], sm[1]), fmaxf(sm[2], sm[3]));
    float4 e;
    e.x = __expf(v.x - M); e.y = __expf(v.y - M);
    e.z = __expf(v.z - M); e.w = __expf(v.w - M);
    float s = e.x + e.y + e.z + e.w;
    #pragma unroll
    for (int off = 32; off > 0; off >>= 1)
        s += __shfl_down(s, off, 64);
    if (lane == 0) ss[wave] = s;
    __syncthreads();
    float inv = 1.f / (ss[0] + ss[1] + ss[2] + ss[3]);
    float4 o;
    o.x = e.x * inv; o.y = e.y * inv; o.z = e.z * inv; o.w = e.w * inv;
    ((float4*)(score + b * LDIM))[t] = o;
}

// vbar[b,h] = sum_l score[b,l] * value[b,l,h]. 8 loads + 8 accumulators in
// flight per thread per iteration (deep MLP), then one atomic set per thread.
__global__ __launch_bounds__(256, 2) void k_vbar(const float4* __restrict__ value,
                                                 const float* __restrict__ score,
                                                 float* __restrict__ vbar) {
    int b  = blockIdx.x >> 4;        // [0,32)
    int lc = blockIdx.x & 15;        // 16 l-chunks of 64
    int t  = threadIdx.x;
    const float4* vrow = value + ((long long)b * LDIM + lc * 64) * 256 + t;
    const float*  sc   = score + b * LDIM + lc * 64;
    float4 acc[8];
    #pragma unroll
    for (int j = 0; j < 8; ++j) acc[j] = make_float4(0.f, 0.f, 0.f, 0.f);
    #pragma unroll 1
    for (int l0 = 0; l0 < 64; l0 += 8) {
        float4 v[8];
        #pragma unroll
        for (int j = 0; j < 8; ++j)
            v[j] = vrow[(long long)(l0 + j) * 256];
        #pragma unroll
        for (int j = 0; j < 8; ++j) {
            float s = sc[l0 + j];
            acc[j].x += s * v[j].x; acc[j].y += s * v[j].y;
            acc[j].z += s * v[j].z; acc[j].w += s * v[j].w;
        }
    }
    float4 a = make_float4(0.f, 0.f, 0.f, 0.f);
    #pragma unroll
    for (int j = 0; j < 8; ++j) {
        a.x += acc[j].x; a.y += acc[j].y; a.z += acc[j].z; a.w += acc[j].w;
    }
    float* dst = vbar + b * HDIM + t * 4;
    atomicAdd(dst + 0, a.x);
    atomicAdd(dst + 1, a.y);
    atomicAdd(dst + 2, a.z);
    atomicAdd(dst + 3, a.w);
}

// result[b,o] = sum_h W[o,h] * vbar[b,h]. One wave per o; W row in registers.
__global__ __launch_bounds__(256, 4) void k_result(const float4* __restrict__ W4,
                                                   const float4* __restrict__ vbar4,
                                                   float* __restrict__ result) {
    int t = threadIdx.x;
    int lane = t & 63, wave = t >> 6;
    int o = blockIdx.x * 4 + wave;   // 256 blocks -> [0,1024)
    float4 w[4];
    #pragma unroll
    for (int i = 0; i < 4; ++i)
        w[i] = W4[o * 256 + lane + 64 * i];
    for (int b = 0; b < BDIM; b += 2) {
        float acc0 = 0.f, acc1 = 0.f;
        #pragma unroll
        for (int i = 0; i < 4; ++i) {
            float4 v0 = vbar4[b * 256 + lane + 64 * i];
            acc0 += v0.x * w[i].x + v0.y * w[i].y + v0.z * w[i].z + v0.w * w[i].w;
            float4 v1 = vbar4[(b + 1) * 256 + lane + 64 * i];
            acc1 += v1.x * w[i].x + v1.y * w[i].y + v1.z * w[i].z + v1.w * w[i].w;
        }
        #pragma unroll
        for (int off = 32; off > 0; off >>= 1) {
            acc0 += __shfl_down(acc0, off, 64);
            acc1 += __shfl_down(acc1, off, 64);
        }
        if (lane == 0) {
            result[b * HDIM + o]       = acc0;
            result[(b + 1) * HDIM + o] = acc1;
        }
    }
}

extern "C" void kernel_launch(void* const* d_in, const int* in_sizes, int n_in,
                              void* d_out, int out_size, void* d_ws, size_t ws_size,
                              hipStream_t stream) {
    const float* query = (const float*)d_in[0];
    const float* key   = (const float*)d_in[1];
    const float* value = (const float*)d_in[2];
    const float* W     = (const float*)d_in[3];
    const float* mlp_w = (const float*)d_in[4];
    const float* mlp_b = (const float*)d_in[5];

    float* out    = (float*)d_out;
    float* result = out;                 // B*H
    float* score  = out + BDIM * LDIM;   // B*L

    float* u1     = (float*)d_ws;
    float* u2     = u1 + HDIM;
    float* vbar   = u2 + HDIM;           // B*H
    float* logits = vbar + BDIM * HDIM;  // B*L

    hipMemsetAsync(d_ws, 0, (size_t)(2 * HDIM + BDIM * HDIM) * sizeof(float), stream);

    k_u12<<<64, 256, 0, stream>>>((const float4*)W, mlp_w, u1, u2);
    k_logits<<<1024, 256, 0, stream>>>((const float4*)query, (const float4*)key,
                                       (const float4*)u1, (const float4*)u2, mlp_b,
                                       (float4*)logits);
    k_softmax<<<BDIM, 256, 0, stream>>>(logits, score);
    k_vbar<<<BDIM * 16, 256, 0, stream>>>((const float4*)value, score, vbar);
    k_result<<<256, 256, 0, stream>>>((const float4*)W, (const float4*)vbar, out);
}